// Round 5
// baseline (3623.475 us; speedup 1.0000x reference)
//
#include <hip/hip_runtime.h>
#include <hip/hip_fp16.h>

// GRU(SEQ=2048, BATCH=64, DIN=128, DH=256) + attention pooling.
//   k_prep_w  : cast W_ih/W_hh -> fp16; fuse b_ih + b_hh(r,z); keep b_hh(n)
//   k_gi      : per seq-chunk: gi16 = mask(data) @ W_ih^T + bias (MFMA f16)
//   k_rnn     : per seq-chunk: 64 WGs x 1024 thr (1/batch elem). thread =
//               (dim j 0..255, K-chunk c 0..3); 96 weight dwords/thread --
//               fits the 128-VGPR cap of a 1024-thread WG (4 waves/SIMD).
//               v_dot2_f32_f16 matvec, DPP quad reduce, gates on c==0 lanes,
//               f32 h state, fp16 h in swizzled LDS, h carried via ws.
//   k_scores  : scores[s][b] = outs16[s][b,:] . w_att
//   k_att     : softmax over s + weighted sum -> d_out (f32 64x256)

#define SEQ   2048
#define BATCH 64
#define DIN   128
#define DH    256
#define G3    768

typedef _Float16 h2 __attribute__((ext_vector_type(2)));
typedef _Float16 h8 __attribute__((ext_vector_type(8)));
typedef float f32x4 __attribute__((ext_vector_type(4)));

#if __has_builtin(__builtin_amdgcn_fdot2)
__device__ __forceinline__ float fd2(unsigned int a, unsigned int b, float c) {
  return __builtin_amdgcn_fdot2(__builtin_bit_cast(h2, a), __builtin_bit_cast(h2, b), c, false);
}
#else
__device__ __forceinline__ float fd2(unsigned int a, unsigned int b, float c) {
  h2 x = __builtin_bit_cast(h2, a), y = __builtin_bit_cast(h2, b);
  return c + (float)x[0] * (float)y[0] + (float)x[1] * (float)y[1];
}
#endif

// quad-perm butterfly add: after <0xB1> then <0x4E>, all 4 lanes of each quad
// hold the 4-lane sum. Pure VALU (no LDS pipe).
template <int CTRL>
__device__ __forceinline__ float dppadd(float x) {
  int t = __builtin_amdgcn_mov_dpp(__builtin_bit_cast(int, x), CTRL, 0xF, 0xF, true);
  return x + __builtin_bit_cast(float, t);
}

// ---------------- prep: weights ----------------
__global__ __launch_bounds__(256) void k_prep_w(const float* __restrict__ wih,
    const float* __restrict__ whh, const float* __restrict__ bih,
    const float* __restrict__ bhh, _Float16* __restrict__ wih16,
    _Float16* __restrict__ whh16, float* __restrict__ biasf,
    float* __restrict__ bhnf) {
  int i = blockIdx.x * 256 + threadIdx.x;
  if (i < 98304) { wih16[i] = (_Float16)wih[i]; return; }
  i -= 98304;
  if (i < 196608) { whh16[i] = (_Float16)whh[i]; return; }
  i -= 196608;
  if (i < 768) { biasf[i] = bih[i] + (i < 512 ? bhh[i] : 0.0f); return; }
  i -= 768;
  if (i < 256) bhnf[i] = bhh[512 + i];
}

// ---------------- gi GEMM over one chunk: rows = CH*64, N=768, K=128 ----------
#define LDK 136  // padded fp16 leading dim

__global__ __launch_bounds__(256) void k_gi(const float* __restrict__ data,
    const _Float16* __restrict__ w16, const float* __restrict__ bias,
    _Float16* __restrict__ gi16, int s0) {
  __shared__ _Float16 As[128][LDK];
  __shared__ _Float16 Ws[64][LDK];
  int tid = threadIdx.x;
  int m0 = blockIdx.x * 128;                 // chunk-local row
  size_t gm0 = (size_t)s0 * 64 + m0;         // global sb row

  // stage A with mask: 2 threads per row, 64 f32 each -> f16
  {
    int r = tid >> 1, c0 = (tid & 1) * 64;
    const float4* src = (const float4*)(data + (gm0 + r) * DIN + c0);
    float last = data[(gm0 + r) * DIN + 127];
    bool msk = (last > 0.0f) && (c0 == 0);
    #pragma unroll
    for (int i = 0; i < 16; ++i) {
      float4 t = src[i];
      if (msk && i >= 8) t = make_float4(0.f, 0.f, 0.f, 0.f);
      union { _Float16 h[4]; uint2 u; } pk;
      pk.h[0] = (_Float16)t.x; pk.h[1] = (_Float16)t.y;
      pk.h[2] = (_Float16)t.z; pk.h[3] = (_Float16)t.w;
      *(uint2*)&As[r][c0 + i * 4] = pk.u;
    }
  }

  int w = tid >> 6, lane = tid & 63;
  int wm = (w >> 1) * 64, wn = (w & 1) * 32;
  int l16 = lane & 15, lhi = lane >> 4;

  for (int nb = 0; nb < 12; ++nb) {
    {
      int r = tid >> 2, cc = (tid & 3) * 32;
      const uint4* src = (const uint4*)(w16 + (size_t)(nb * 64 + r) * DIN + cc);
      #pragma unroll
      for (int i = 0; i < 4; ++i)
        *(uint4*)&Ws[r][cc + i * 8] = src[i];
    }
    __syncthreads();

    f32x4 acc[4][2];
    #pragma unroll
    for (int mi = 0; mi < 4; ++mi)
      #pragma unroll
      for (int ni = 0; ni < 2; ++ni)
        acc[mi][ni] = (f32x4){0.f, 0.f, 0.f, 0.f};

    #pragma unroll
    for (int ks = 0; ks < 4; ++ks) {
      int kk = ks * 32 + lhi * 8;
      h8 a[4], bfr[2];
      #pragma unroll
      for (int mi = 0; mi < 4; ++mi)
        a[mi] = *(const h8*)&As[wm + mi * 16 + l16][kk];
      #pragma unroll
      for (int ni = 0; ni < 2; ++ni)
        bfr[ni] = *(const h8*)&Ws[wn + ni * 16 + l16][kk];
      #pragma unroll
      for (int mi = 0; mi < 4; ++mi)
        #pragma unroll
        for (int ni = 0; ni < 2; ++ni)
          acc[mi][ni] = __builtin_amdgcn_mfma_f32_16x16x32_f16(a[mi], bfr[ni], acc[mi][ni], 0, 0, 0);
    }

    #pragma unroll
    for (int mi = 0; mi < 4; ++mi)
      #pragma unroll
      for (int ni = 0; ni < 2; ++ni) {
        int col = nb * 64 + wn + ni * 16 + l16;
        float bv = bias[col];
        #pragma unroll
        for (int r = 0; r < 4; ++r) {
          int row = m0 + wm + mi * 16 + lhi * 4 + r;
          gi16[(size_t)row * G3 + col] = (_Float16)(acc[mi][ni][r] + bv);
        }
      }
    __syncthreads();
  }
}

// ---------------- recurrent kernel over one chunk ----------------
// 1024 threads: thread = (dim j = tid>>2 in 0..255, K-chunk c = tid&3).
// Weights: 3 gates x 64 fp16 = 96 dwords/thread, under the 128-VGPR cap
// (1024-thread WG forces 4 waves/SIMD -> cap 512/4 = 128).
// h: fp16 in bank-swizzled LDS (quarter c at dword offset c*36); f32 state
// on c==0 lanes; gates + writes on c==0 lanes only.
__global__ __launch_bounds__(1024, 4) void k_rnn(const _Float16* __restrict__ whh16,
    const _Float16* __restrict__ gi16, const float* __restrict__ bhnf,
    _Float16* __restrict__ outs16, float* __restrict__ hstate, int s0, int CH) {
  __shared__ __align__(16) unsigned int hsh[2][144];
  int b = blockIdx.x;
  int tid = threadIdx.x;
  int c = tid & 3;
  int j = tid >> 2;   // 0..255

  // weights: gate rows j, 256+j, 512+j; K-chunk c*64..c*64+63 -> 8 uint4 each
  uint4 wr_[8], wz_[8], wn_[8];
  {
    const uint4* pr = (const uint4*)(whh16 + (size_t)j * DH + c * 64);
    const uint4* pz = (const uint4*)(whh16 + (size_t)(256 + j) * DH + c * 64);
    const uint4* pn = (const uint4*)(whh16 + (size_t)(512 + j) * DH + c * 64);
    #pragma unroll
    for (int i = 0; i < 8; ++i) { wr_[i] = pr[i]; wz_[i] = pz[i]; wn_[i] = pn[i]; }
  }
  #pragma unroll
  for (int i = 0; i < 8; ++i) {
    asm volatile("" : "+v"(wr_[i].x), "+v"(wr_[i].y), "+v"(wr_[i].z), "+v"(wr_[i].w));
    asm volatile("" : "+v"(wz_[i].x), "+v"(wz_[i].y), "+v"(wz_[i].z), "+v"(wz_[i].w));
    asm volatile("" : "+v"(wn_[i].x), "+v"(wn_[i].y), "+v"(wn_[i].z), "+v"(wn_[i].w));
  }

  // LDS write slot for this dim: dword d=j>>1 at phys (d>>5)*36+(d&31), half j&1
  int dj = j >> 1;
  int wbyte = ((dj >> 5) * 36 + (dj & 31)) * 4 + (j & 1) * 2;

  float bn = 0.f, h = 0.f;
  if (c == 0) {
    bn = bhnf[j];
    h = (s0 == 0) ? 0.f : hstate[b * 256 + j];
    *(_Float16*)((char*)&hsh[0][0] + wbyte) = (_Float16)h;
  }
  __syncthreads();

  const _Float16* gp = gi16 + (size_t)b * G3 + j;                 // chunk-local
  _Float16* op = outs16 + ((size_t)s0 * 64 + b) * DH + j;         // global
  int p = 0;

  for (int s = 0; s < CH; ++s) {
    float gr = 0.f, gz = 0.f, gn = 0.f;
    if (c == 0) {           // issue early; latency hides under the dot phase
      gr = (float)gp[0];
      gz = (float)gp[256];
      gn = (float)gp[512];
    }

    const uint4* hp = (const uint4*)&hsh[p][c * 36];
    float ar = 0.f, az = 0.f, an = 0.f;
    #pragma unroll
    for (int u = 0; u < 8; ++u) {
      uint4 hv = hp[u];
      ar = fd2(wr_[u].x, hv.x, ar); ar = fd2(wr_[u].y, hv.y, ar);
      ar = fd2(wr_[u].z, hv.z, ar); ar = fd2(wr_[u].w, hv.w, ar);
      az = fd2(wz_[u].x, hv.x, az); az = fd2(wz_[u].y, hv.y, az);
      az = fd2(wz_[u].z, hv.z, az); az = fd2(wz_[u].w, hv.w, az);
      an = fd2(wn_[u].x, hv.x, an); an = fd2(wn_[u].y, hv.y, an);
      an = fd2(wn_[u].z, hv.z, an); an = fd2(wn_[u].w, hv.w, an);
    }
    // 4-lane (K-chunk) butterfly via DPP quad_perm
    ar = dppadd<0xB1>(ar); ar = dppadd<0x4E>(ar);
    az = dppadd<0xB1>(az); az = dppadd<0x4E>(az);
    an = dppadd<0xB1>(an); an = dppadd<0x4E>(an);

    if (c == 0) {
      float r = 1.f / (1.f + __expf(-(gr + ar)));
      float z = 1.f / (1.f + __expf(-(gz + az)));
      float x = gn + r * (an + bn);
      float n = 1.f - 2.f / (__expf(2.f * x) + 1.f);
      h = n + z * (h - n);
      _Float16 h16 = (_Float16)h;
      *(_Float16*)((char*)&hsh[p ^ 1][0] + wbyte) = h16;
      op[0] = h16;
    }
    __syncthreads();
    p ^= 1;
    gp += 64 * G3;
    op += 64 * DH;
  }

  if (c == 0) hstate[b * 256 + j] = h;
}

// ---------------- attention: scores ----------------
__global__ __launch_bounds__(256) void k_scores(const _Float16* __restrict__ outs16,
    const float* __restrict__ watt, float* __restrict__ scores) {
  int idx = blockIdx.x * 4 + (threadIdx.x >> 6);  // sb index
  int lane = threadIdx.x & 63;
  const uint2* row = (const uint2*)((const unsigned int*)outs16 + (size_t)idx * 128 + lane * 2);
  uint2 v = *row;
  float4 w = *(const float4*)(watt + lane * 4);
  h2 va = __builtin_bit_cast(h2, v.x);
  h2 vb = __builtin_bit_cast(h2, v.y);
  float sum = (float)va[0] * w.x + (float)va[1] * w.y + (float)vb[0] * w.z + (float)vb[1] * w.w;
  #pragma unroll
  for (int m = 1; m < 64; m <<= 1) sum += __shfl_xor(sum, m);
  if (lane == 0) scores[idx] = sum;
}

// ---------------- attention: softmax + weighted sum ----------------
__global__ __launch_bounds__(256) void k_att(const _Float16* __restrict__ outs16,
    const float* __restrict__ scores, float* __restrict__ out) {
  __shared__ float al[SEQ];
  __shared__ float red[12];
  int b = blockIdx.x, t = threadIdx.x;
  float v[8];
  float m = -1e30f;
  #pragma unroll
  for (int i = 0; i < 8; ++i) {
    v[i] = scores[(size_t)(t + i * 256) * 64 + b];
    m = fmaxf(m, v[i]);
  }
  #pragma unroll
  for (int k = 1; k < 64; k <<= 1) m = fmaxf(m, __shfl_xor(m, k));
  if ((t & 63) == 0) red[t >> 6] = m;
  __syncthreads();
  m = fmaxf(fmaxf(red[0], red[1]), fmaxf(red[2], red[3]));
  float l = 0.f;
  #pragma unroll
  for (int i = 0; i < 8; ++i) {
    float e = __expf(v[i] - m);
    al[t + i * 256] = e;
    l += e;
  }
  #pragma unroll
  for (int k = 1; k < 64; k <<= 1) l += __shfl_xor(l, k);
  if ((t & 63) == 0) red[8 + (t >> 6)] = l;
  __syncthreads();
  l = red[8] + red[9] + red[10] + red[11];
  float inv = 1.f / l;

  float acc = 0.f;
  const unsigned int* o32 = (const unsigned int*)outs16;
  size_t base = (size_t)b * 128 + (t >> 1);
  int hi = t & 1;
  for (int s = 0; s < SEQ; ++s) {
    unsigned int u = o32[base + (size_t)s * 8192];
    h2 hh = __builtin_bit_cast(h2, u);
    acc += al[s] * (float)hh[hi];
  }
  out[b * 256 + t] = acc * inv;
}

__global__ __launch_bounds__(256) void k_fill(float* out, float v, int n) {
  int i = blockIdx.x * 256 + threadIdx.x;
  if (i < n) out[i] = v;
}

// ---------------- launch ----------------
extern "C" void kernel_launch(void* const* d_in, const int* in_sizes, int n_in,
                              void* d_out, int out_size, void* d_ws, size_t ws_size,
                              hipStream_t stream) {
  const float* data = (const float*)d_in[0];
  const float* wih  = (const float*)d_in[1];
  const float* whh  = (const float*)d_in[2];
  const float* bih  = (const float*)d_in[3];
  const float* bhh  = (const float*)d_in[4];
  const float* watt = (const float*)d_in[5];
  float* out = (float*)d_out;

  const size_t OFF_WIH    = 0;           //    196,608
  const size_t OFF_WHH    = 196608;      //    393,216
  const size_t OFF_BIAS   = 589824;      //      3,072
  const size_t OFF_BHN    = 592896;      //      1,024
  const size_t OFF_H      = 593920;      //     65,536
  const size_t OFF_SCORES = 659456;      //    524,288
  const size_t OFF_OUTS   = 1183744;     // 67,108,864
  const size_t OFF_GI     = 68292608;

  int CH = 0;
  for (int ch = SEQ; ch >= 64; ch >>= 1) {
    if (OFF_GI + (size_t)ch * 64 * G3 * 2 <= ws_size) { CH = ch; break; }
  }
  if (CH == 0) {
    k_fill<<<(out_size + 255) / 256, 256, 0, stream>>>(out, 2.0e6f, out_size);
    return;
  }

  char* ws = (char*)d_ws;
  _Float16* wih16  = (_Float16*)(ws + OFF_WIH);
  _Float16* whh16  = (_Float16*)(ws + OFF_WHH);
  float*    biasf  = (float*)(ws + OFF_BIAS);
  float*    bhnf   = (float*)(ws + OFF_BHN);
  float*    hstate = (float*)(ws + OFF_H);
  float*    scores = (float*)(ws + OFF_SCORES);
  _Float16* outs16 = (_Float16*)(ws + OFF_OUTS);
  _Float16* gi16   = (_Float16*)(ws + OFF_GI);

  k_prep_w<<<(98304 + 196608 + 768 + 256 + 255) / 256, 256, 0, stream>>>(
      wih, whh, bih, bhh, wih16, whh16, biasf, bhnf);

  for (int s0 = 0; s0 < SEQ; s0 += CH) {
    k_gi<<<CH * 64 / 128, 256, 0, stream>>>(data, wih16, biasf, gi16, s0);
    k_rnn<<<BATCH, 1024, 0, stream>>>(whh16, gi16, bhnf, outs16, hstate, s0, CH);
  }

  k_scores<<<SEQ * BATCH / 4, 256, 0, stream>>>(outs16, watt, scores);
  k_att<<<BATCH, 256, 0, stream>>>(outs16, scores, out);
}

// Round 6
// 3566.039 us; speedup vs baseline: 1.0161x; 1.0161x over previous
//
#include <hip/hip_runtime.h>
#include <hip/hip_fp16.h>

// GRU(SEQ=2048, BATCH=64, DIN=128, DH=256) + attention pooling.
//   k_prep_w  : cast W_ih/W_hh -> fp16; fuse b_ih + b_hh(r,z); keep b_hh(n)
//   k_gi      : per seq-chunk: gi16 = mask(data) @ W_ih^T + bias (MFMA f16)
//   k_rnn     : per seq-chunk: 64 WGs x 512 thr (1/batch elem). thread =
//               (dim-pair Q 0..127, K-chunk c 0..3); 192 weight dwords/thread
//               held in VGPRs, kept resident by IN-LOOP asm pins (loop-carried
//               opaque redefinition -> rematerialization impossible).
//               v_dot2_f32_f16 matvec, DPP quad reduce, f32 h state,
//               fp16 h in swizzled LDS, h carried across chunks via ws.
//   k_scores  : scores[s][b] = outs16[s][b,:] . w_att
//   k_att     : softmax over s + weighted sum -> d_out (f32 64x256)

#define SEQ   2048
#define BATCH 64
#define DIN   128
#define DH    256
#define G3    768

typedef _Float16 h2 __attribute__((ext_vector_type(2)));
typedef _Float16 h8 __attribute__((ext_vector_type(8)));
typedef float f32x4 __attribute__((ext_vector_type(4)));

#if __has_builtin(__builtin_amdgcn_fdot2)
__device__ __forceinline__ float fd2(unsigned int a, unsigned int b, float c) {
  return __builtin_amdgcn_fdot2(__builtin_bit_cast(h2, a), __builtin_bit_cast(h2, b), c, false);
}
#else
__device__ __forceinline__ float fd2(unsigned int a, unsigned int b, float c) {
  h2 x = __builtin_bit_cast(h2, a), y = __builtin_bit_cast(h2, b);
  return c + (float)x[0] * (float)y[0] + (float)x[1] * (float)y[1];
}
#endif

// quad-perm butterfly add: after <0xB1> then <0x4E>, all 4 lanes of each quad
// hold the 4-lane sum. Pure VALU (no LDS pipe).
template <int CTRL>
__device__ __forceinline__ float dppadd(float x) {
  int t = __builtin_amdgcn_mov_dpp(__builtin_bit_cast(int, x), CTRL, 0xF, 0xF, true);
  return x + __builtin_bit_cast(float, t);
}

// ---------------- prep: weights ----------------
__global__ __launch_bounds__(256) void k_prep_w(const float* __restrict__ wih,
    const float* __restrict__ whh, const float* __restrict__ bih,
    const float* __restrict__ bhh, _Float16* __restrict__ wih16,
    _Float16* __restrict__ whh16, float* __restrict__ biasf,
    float* __restrict__ bhnf) {
  int i = blockIdx.x * 256 + threadIdx.x;
  if (i < 98304) { wih16[i] = (_Float16)wih[i]; return; }
  i -= 98304;
  if (i < 196608) { whh16[i] = (_Float16)whh[i]; return; }
  i -= 196608;
  if (i < 768) { biasf[i] = bih[i] + (i < 512 ? bhh[i] : 0.0f); return; }
  i -= 768;
  if (i < 256) bhnf[i] = bhh[512 + i];
}

// ---------------- gi GEMM over one chunk: rows = CH*64, N=768, K=128 ----------
#define LDK 136  // padded fp16 leading dim

__global__ __launch_bounds__(256) void k_gi(const float* __restrict__ data,
    const _Float16* __restrict__ w16, const float* __restrict__ bias,
    _Float16* __restrict__ gi16, int s0) {
  __shared__ _Float16 As[128][LDK];
  __shared__ _Float16 Ws[64][LDK];
  int tid = threadIdx.x;
  int m0 = blockIdx.x * 128;                 // chunk-local row
  size_t gm0 = (size_t)s0 * 64 + m0;         // global sb row

  // stage A with mask: 2 threads per row, 64 f32 each -> f16
  {
    int r = tid >> 1, c0 = (tid & 1) * 64;
    const float4* src = (const float4*)(data + (gm0 + r) * DIN + c0);
    float last = data[(gm0 + r) * DIN + 127];
    bool msk = (last > 0.0f) && (c0 == 0);
    #pragma unroll
    for (int i = 0; i < 16; ++i) {
      float4 t = src[i];
      if (msk && i >= 8) t = make_float4(0.f, 0.f, 0.f, 0.f);
      union { _Float16 h[4]; uint2 u; } pk;
      pk.h[0] = (_Float16)t.x; pk.h[1] = (_Float16)t.y;
      pk.h[2] = (_Float16)t.z; pk.h[3] = (_Float16)t.w;
      *(uint2*)&As[r][c0 + i * 4] = pk.u;
    }
  }

  int w = tid >> 6, lane = tid & 63;
  int wm = (w >> 1) * 64, wn = (w & 1) * 32;
  int l16 = lane & 15, lhi = lane >> 4;

  for (int nb = 0; nb < 12; ++nb) {
    {
      int r = tid >> 2, cc = (tid & 3) * 32;
      const uint4* src = (const uint4*)(w16 + (size_t)(nb * 64 + r) * DIN + cc);
      #pragma unroll
      for (int i = 0; i < 4; ++i)
        *(uint4*)&Ws[r][cc + i * 8] = src[i];
    }
    __syncthreads();

    f32x4 acc[4][2];
    #pragma unroll
    for (int mi = 0; mi < 4; ++mi)
      #pragma unroll
      for (int ni = 0; ni < 2; ++ni)
        acc[mi][ni] = (f32x4){0.f, 0.f, 0.f, 0.f};

    #pragma unroll
    for (int ks = 0; ks < 4; ++ks) {
      int kk = ks * 32 + lhi * 8;
      h8 a[4], bfr[2];
      #pragma unroll
      for (int mi = 0; mi < 4; ++mi)
        a[mi] = *(const h8*)&As[wm + mi * 16 + l16][kk];
      #pragma unroll
      for (int ni = 0; ni < 2; ++ni)
        bfr[ni] = *(const h8*)&Ws[wn + ni * 16 + l16][kk];
      #pragma unroll
      for (int mi = 0; mi < 4; ++mi)
        #pragma unroll
        for (int ni = 0; ni < 2; ++ni)
          acc[mi][ni] = __builtin_amdgcn_mfma_f32_16x16x32_f16(a[mi], bfr[ni], acc[mi][ni], 0, 0, 0);
    }

    #pragma unroll
    for (int mi = 0; mi < 4; ++mi)
      #pragma unroll
      for (int ni = 0; ni < 2; ++ni) {
        int col = nb * 64 + wn + ni * 16 + l16;
        float bv = bias[col];
        #pragma unroll
        for (int r = 0; r < 4; ++r) {
          int row = m0 + wm + mi * 16 + lhi * 4 + r;
          gi16[(size_t)row * G3 + col] = (_Float16)(acc[mi][ni][r] + bv);
        }
      }
    __syncthreads();
  }
}

// ---------------- recurrent kernel over one chunk ----------------
// 512 threads: thread = (Q = dim-pair 0..127, c = K-chunk 0..3).
// Weights: 6 gate-rows x 64 fp16 = 192 dwords/thread in VGPRs (cap 256 at
// 2 waves/EU). IN-LOOP asm pins make the values loop-carried through an
// opaque asm so the compiler cannot rematerialize them from memory.
__global__ __launch_bounds__(512, 2) void k_rnn(const _Float16* __restrict__ whh16,
    const _Float16* __restrict__ gi16, const float* __restrict__ bhnf,
    _Float16* __restrict__ outs16, float* __restrict__ hstate, int s0, int CH) {
  // logical dword D (f16-pair index 0..127) at phys (D>>5)*36 + (D&31)
  __shared__ __align__(16) unsigned int hsh[2][144];
  int b = blockIdx.x;
  int tid = threadIdx.x;
  int lane = tid & 63;
  int c = lane & 3;
  int Q = (tid >> 6) * 16 + (lane >> 2);  // 0..127
  int j0 = 2 * Q;

  uint4 wv[6][8];
  #pragma unroll
  for (int d = 0; d < 2; ++d)
    #pragma unroll
    for (int g = 0; g < 3; ++g) {
      const uint4* src = (const uint4*)(whh16 + (size_t)(g * 256 + j0 + d) * DH + c * 64);
      #pragma unroll
      for (int i = 0; i < 8; ++i) wv[d * 3 + g][i] = src[i];
    }

  float bn0 = bhnf[j0], bn1 = bhnf[j0 + 1];
  float h0, h1;
  if (s0 == 0) { h0 = 0.f; h1 = 0.f; }
  else { h0 = hstate[b * 256 + j0]; h1 = hstate[b * 256 + j0 + 1]; }

  int wr = (Q >> 5) * 36 + (Q & 31);  // phys write slot for this thread's pair
  if (c == 0) {
    union { _Float16 h[2]; unsigned int u; } pk;
    pk.h[0] = (_Float16)h0; pk.h[1] = (_Float16)h1;
    hsh[0][wr] = pk.u;
  }
  __syncthreads();

  const unsigned int* gi32 = (const unsigned int*)gi16;
  unsigned int* outs32 = (unsigned int*)outs16;
  size_t gbase = (size_t)b * 384 + Q;                       // chunk-local
  size_t obase = ((size_t)s0 * 64 + b) * 128 + Q;           // global
  int p = 0;

  for (int s = 0; s < CH; ++s) {
    // IN-LOOP PIN: loop-carried opaque redefinition of all 192 weight dwords.
    // Zero instructions; makes remat-from-memory illegal, forcing residency.
    #pragma unroll
    for (int g = 0; g < 6; ++g)
      #pragma unroll
      for (int i = 0; i < 8; ++i)
        asm volatile("" : "+v"(wv[g][i].x), "+v"(wv[g][i].y),
                          "+v"(wv[g][i].z), "+v"(wv[g][i].w));

    unsigned int gr = gi32[gbase];
    unsigned int gz = gi32[gbase + 128];
    unsigned int gn = gi32[gbase + 256];

    const uint4* hp = (const uint4*)&hsh[p][c * 36];
    float a0 = 0.f, a1 = 0.f, a2 = 0.f, a3 = 0.f, a4 = 0.f, a5 = 0.f;
    #pragma unroll
    for (int u = 0; u < 8; ++u) {
      uint4 hv = hp[u];
      a0 = fd2(wv[0][u].x, hv.x, a0); a0 = fd2(wv[0][u].y, hv.y, a0);
      a0 = fd2(wv[0][u].z, hv.z, a0); a0 = fd2(wv[0][u].w, hv.w, a0);
      a1 = fd2(wv[1][u].x, hv.x, a1); a1 = fd2(wv[1][u].y, hv.y, a1);
      a1 = fd2(wv[1][u].z, hv.z, a1); a1 = fd2(wv[1][u].w, hv.w, a1);
      a2 = fd2(wv[2][u].x, hv.x, a2); a2 = fd2(wv[2][u].y, hv.y, a2);
      a2 = fd2(wv[2][u].z, hv.z, a2); a2 = fd2(wv[2][u].w, hv.w, a2);
      a3 = fd2(wv[3][u].x, hv.x, a3); a3 = fd2(wv[3][u].y, hv.y, a3);
      a3 = fd2(wv[3][u].z, hv.z, a3); a3 = fd2(wv[3][u].w, hv.w, a3);
      a4 = fd2(wv[4][u].x, hv.x, a4); a4 = fd2(wv[4][u].y, hv.y, a4);
      a4 = fd2(wv[4][u].z, hv.z, a4); a4 = fd2(wv[4][u].w, hv.w, a4);
      a5 = fd2(wv[5][u].x, hv.x, a5); a5 = fd2(wv[5][u].y, hv.y, a5);
      a5 = fd2(wv[5][u].z, hv.z, a5); a5 = fd2(wv[5][u].w, hv.w, a5);
    }
    // 4-lane butterfly via DPP quad_perm (pure VALU, sum lands in all 4 lanes)
    a0 = dppadd<0xB1>(a0); a0 = dppadd<0x4E>(a0);
    a1 = dppadd<0xB1>(a1); a1 = dppadd<0x4E>(a1);
    a2 = dppadd<0xB1>(a2); a2 = dppadd<0x4E>(a2);
    a3 = dppadd<0xB1>(a3); a3 = dppadd<0x4E>(a3);
    a4 = dppadd<0xB1>(a4); a4 = dppadd<0x4E>(a4);
    a5 = dppadd<0xB1>(a5); a5 = dppadd<0x4E>(a5);

    h2 grh = __builtin_bit_cast(h2, gr);
    h2 gzh = __builtin_bit_cast(h2, gz);
    h2 gnh = __builtin_bit_cast(h2, gn);
    {
      float r = 1.f / (1.f + __expf(-((float)grh[0] + a0)));
      float z = 1.f / (1.f + __expf(-((float)gzh[0] + a1)));
      float x = (float)gnh[0] + r * (a2 + bn0);
      float n = 1.f - 2.f / (__expf(2.f * x) + 1.f);
      h0 = n + z * (h0 - n);
    }
    {
      float r = 1.f / (1.f + __expf(-((float)grh[1] + a3)));
      float z = 1.f / (1.f + __expf(-((float)gzh[1] + a4)));
      float x = (float)gnh[1] + r * (a5 + bn1);
      float n = 1.f - 2.f / (__expf(2.f * x) + 1.f);
      h1 = n + z * (h1 - n);
    }
    union { _Float16 h[2]; unsigned int u; } pk;
    pk.h[0] = (_Float16)h0; pk.h[1] = (_Float16)h1;
    if (c == 0) {
      hsh[p ^ 1][wr] = pk.u;
      outs32[obase] = pk.u;
    }
    __syncthreads();
    p ^= 1;
    gbase += 64 * 384;
    obase += 64 * 128;
  }

  if (c == 0) {
    hstate[b * 256 + j0] = h0;
    hstate[b * 256 + j0 + 1] = h1;
  }
}

// ---------------- attention: scores ----------------
__global__ __launch_bounds__(256) void k_scores(const _Float16* __restrict__ outs16,
    const float* __restrict__ watt, float* __restrict__ scores) {
  int idx = blockIdx.x * 4 + (threadIdx.x >> 6);  // sb index
  int lane = threadIdx.x & 63;
  const uint2* row = (const uint2*)((const unsigned int*)outs16 + (size_t)idx * 128 + lane * 2);
  uint2 v = *row;
  float4 w = *(const float4*)(watt + lane * 4);
  h2 va = __builtin_bit_cast(h2, v.x);
  h2 vb = __builtin_bit_cast(h2, v.y);
  float sum = (float)va[0] * w.x + (float)va[1] * w.y + (float)vb[0] * w.z + (float)vb[1] * w.w;
  #pragma unroll
  for (int m = 1; m < 64; m <<= 1) sum += __shfl_xor(sum, m);
  if (lane == 0) scores[idx] = sum;
}

// ---------------- attention: softmax + weighted sum ----------------
__global__ __launch_bounds__(256) void k_att(const _Float16* __restrict__ outs16,
    const float* __restrict__ scores, float* __restrict__ out) {
  __shared__ float al[SEQ];
  __shared__ float red[12];
  int b = blockIdx.x, t = threadIdx.x;
  float v[8];
  float m = -1e30f;
  #pragma unroll
  for (int i = 0; i < 8; ++i) {
    v[i] = scores[(size_t)(t + i * 256) * 64 + b];
    m = fmaxf(m, v[i]);
  }
  #pragma unroll
  for (int k = 1; k < 64; k <<= 1) m = fmaxf(m, __shfl_xor(m, k));
  if ((t & 63) == 0) red[t >> 6] = m;
  __syncthreads();
  m = fmaxf(fmaxf(red[0], red[1]), fmaxf(red[2], red[3]));
  float l = 0.f;
  #pragma unroll
  for (int i = 0; i < 8; ++i) {
    float e = __expf(v[i] - m);
    al[t + i * 256] = e;
    l += e;
  }
  #pragma unroll
  for (int k = 1; k < 64; k <<= 1) l += __shfl_xor(l, k);
  if ((t & 63) == 0) red[8 + (t >> 6)] = l;
  __syncthreads();
  l = red[8] + red[9] + red[10] + red[11];
  float inv = 1.f / l;

  float acc = 0.f;
  const unsigned int* o32 = (const unsigned int*)outs16;
  size_t base = (size_t)b * 128 + (t >> 1);
  int hi = t & 1;
  for (int s = 0; s < SEQ; ++s) {
    unsigned int u = o32[base + (size_t)s * 8192];
    h2 hh = __builtin_bit_cast(h2, u);
    acc += al[s] * (float)hh[hi];
  }
  out[b * 256 + t] = acc * inv;
}

__global__ __launch_bounds__(256) void k_fill(float* out, float v, int n) {
  int i = blockIdx.x * 256 + threadIdx.x;
  if (i < n) out[i] = v;
}

// ---------------- launch ----------------
extern "C" void kernel_launch(void* const* d_in, const int* in_sizes, int n_in,
                              void* d_out, int out_size, void* d_ws, size_t ws_size,
                              hipStream_t stream) {
  const float* data = (const float*)d_in[0];
  const float* wih  = (const float*)d_in[1];
  const float* whh  = (const float*)d_in[2];
  const float* bih  = (const float*)d_in[3];
  const float* bhh  = (const float*)d_in[4];
  const float* watt = (const float*)d_in[5];
  float* out = (float*)d_out;

  const size_t OFF_WIH    = 0;           //    196,608
  const size_t OFF_WHH    = 196608;      //    393,216
  const size_t OFF_BIAS   = 589824;      //      3,072
  const size_t OFF_BHN    = 592896;      //      1,024
  const size_t OFF_H      = 593920;      //     65,536
  const size_t OFF_SCORES = 659456;      //    524,288
  const size_t OFF_OUTS   = 1183744;     // 67,108,864
  const size_t OFF_GI     = 68292608;

  int CH = 0;
  for (int ch = SEQ; ch >= 64; ch >>= 1) {
    if (OFF_GI + (size_t)ch * 64 * G3 * 2 <= ws_size) { CH = ch; break; }
  }
  if (CH == 0) {
    k_fill<<<(out_size + 255) / 256, 256, 0, stream>>>(out, 2.0e6f, out_size);
    return;
  }

  char* ws = (char*)d_ws;
  _Float16* wih16  = (_Float16*)(ws + OFF_WIH);
  _Float16* whh16  = (_Float16*)(ws + OFF_WHH);
  float*    biasf  = (float*)(ws + OFF_BIAS);
  float*    bhnf   = (float*)(ws + OFF_BHN);
  float*    hstate = (float*)(ws + OFF_H);
  float*    scores = (float*)(ws + OFF_SCORES);
  _Float16* outs16 = (_Float16*)(ws + OFF_OUTS);
  _Float16* gi16   = (_Float16*)(ws + OFF_GI);

  k_prep_w<<<(98304 + 196608 + 768 + 256 + 255) / 256, 256, 0, stream>>>(
      wih, whh, bih, bhh, wih16, whh16, biasf, bhnf);

  for (int s0 = 0; s0 < SEQ; s0 += CH) {
    k_gi<<<CH * 64 / 128, 256, 0, stream>>>(data, wih16, biasf, gi16, s0);
    k_rnn<<<BATCH, 512, 0, stream>>>(whh16, gi16, bhnf, outs16, hstate, s0, CH);
  }

  k_scores<<<SEQ * BATCH / 4, 256, 0, stream>>>(outs16, watt, scores);
  k_att<<<BATCH, 256, 0, stream>>>(outs16, scores, out);
}

// Round 7
// 3319.262 us; speedup vs baseline: 1.0917x; 1.0743x over previous
//
#include <hip/hip_runtime.h>
#include <hip/hip_fp16.h>

// GRU(SEQ=2048, BATCH=64, DIN=128, DH=256) + attention pooling.
//   k_prep_w  : cast W_ih/W_hh -> fp16; fuse b_ih + b_hh(r,z); keep b_hh(n)
//   k_gi      : per seq-chunk: gi16 = mask(data) @ W_ih^T + bias (MFMA f16)
//   k_rnn     : per seq-chunk: 64 WGs x 512 thr (1/batch elem). thread =
//               (dim-pair Q 0..127, K-chunk c 0..3); 192 weight dwords/thread
//               pinned to EXPLICIT physical VGPRs v64..v255 via in-loop asm
//               (defeats the allocator's AGPR-parking of class-"v" pins seen
//               in rounds 4-6: VGPR_Count stayed 112/64 with ~384 shuttle
//               moves per step). v_dot2_f32_f16 matvec, DPP quad reduce,
//               f32 h state, fp16 h in swizzled LDS, h carried via ws.
//   k_scores  : scores[s][b] = outs16[s][b,:] . w_att
//   k_att     : softmax over s + weighted sum -> d_out (f32 64x256)

#define SEQ   2048
#define BATCH 64
#define DIN   128
#define DH    256
#define G3    768

typedef _Float16 h2 __attribute__((ext_vector_type(2)));
typedef _Float16 h8 __attribute__((ext_vector_type(8)));
typedef float f32x4 __attribute__((ext_vector_type(4)));

#if __has_builtin(__builtin_amdgcn_fdot2)
__device__ __forceinline__ float fd2(unsigned int a, unsigned int b, float c) {
  return __builtin_amdgcn_fdot2(__builtin_bit_cast(h2, a), __builtin_bit_cast(h2, b), c, false);
}
#else
__device__ __forceinline__ float fd2(unsigned int a, unsigned int b, float c) {
  h2 x = __builtin_bit_cast(h2, a), y = __builtin_bit_cast(h2, b);
  return c + (float)x[0] * (float)y[0] + (float)x[1] * (float)y[1];
}
#endif

// quad-perm butterfly add: after <0xB1> then <0x4E>, all 4 lanes of each quad
// hold the 4-lane sum. Pure VALU (no LDS pipe).
template <int CTRL>
__device__ __forceinline__ float dppadd(float x) {
  int t = __builtin_amdgcn_mov_dpp(__builtin_bit_cast(int, x), CTRL, 0xF, 0xF, true);
  return x + __builtin_bit_cast(float, t);
}

// Pin a uint4 to four consecutive EXPLICIT physical VGPRs. Zero instructions;
// forces the allocator to keep the values in exactly these registers at this
// program point (AGPR parking would need copies around every asm -> residency
// is the only cheap allocation).
#define PIN4(v4, r0, r1, r2, r3)                                   \
  asm volatile("" : "+{v" #r0 "}"(v4.x), "+{v" #r1 "}"(v4.y),      \
                    "+{v" #r2 "}"(v4.z), "+{v" #r3 "}"(v4.w))

// ---------------- prep: weights ----------------
__global__ __launch_bounds__(256) void k_prep_w(const float* __restrict__ wih,
    const float* __restrict__ whh, const float* __restrict__ bih,
    const float* __restrict__ bhh, _Float16* __restrict__ wih16,
    _Float16* __restrict__ whh16, float* __restrict__ biasf,
    float* __restrict__ bhnf) {
  int i = blockIdx.x * 256 + threadIdx.x;
  if (i < 98304) { wih16[i] = (_Float16)wih[i]; return; }
  i -= 98304;
  if (i < 196608) { whh16[i] = (_Float16)whh[i]; return; }
  i -= 196608;
  if (i < 768) { biasf[i] = bih[i] + (i < 512 ? bhh[i] : 0.0f); return; }
  i -= 768;
  if (i < 256) bhnf[i] = bhh[512 + i];
}

// ---------------- gi GEMM over one chunk: rows = CH*64, N=768, K=128 ----------
#define LDK 136  // padded fp16 leading dim

__global__ __launch_bounds__(256) void k_gi(const float* __restrict__ data,
    const _Float16* __restrict__ w16, const float* __restrict__ bias,
    _Float16* __restrict__ gi16, int s0) {
  __shared__ _Float16 As[128][LDK];
  __shared__ _Float16 Ws[64][LDK];
  int tid = threadIdx.x;
  int m0 = blockIdx.x * 128;                 // chunk-local row
  size_t gm0 = (size_t)s0 * 64 + m0;         // global sb row

  // stage A with mask: 2 threads per row, 64 f32 each -> f16
  {
    int r = tid >> 1, c0 = (tid & 1) * 64;
    const float4* src = (const float4*)(data + (gm0 + r) * DIN + c0);
    float last = data[(gm0 + r) * DIN + 127];
    bool msk = (last > 0.0f) && (c0 == 0);
    #pragma unroll
    for (int i = 0; i < 16; ++i) {
      float4 t = src[i];
      if (msk && i >= 8) t = make_float4(0.f, 0.f, 0.f, 0.f);
      union { _Float16 h[4]; uint2 u; } pk;
      pk.h[0] = (_Float16)t.x; pk.h[1] = (_Float16)t.y;
      pk.h[2] = (_Float16)t.z; pk.h[3] = (_Float16)t.w;
      *(uint2*)&As[r][c0 + i * 4] = pk.u;
    }
  }

  int w = tid >> 6, lane = tid & 63;
  int wm = (w >> 1) * 64, wn = (w & 1) * 32;
  int l16 = lane & 15, lhi = lane >> 4;

  for (int nb = 0; nb < 12; ++nb) {
    {
      int r = tid >> 2, cc = (tid & 3) * 32;
      const uint4* src = (const uint4*)(w16 + (size_t)(nb * 64 + r) * DIN + cc);
      #pragma unroll
      for (int i = 0; i < 4; ++i)
        *(uint4*)&Ws[r][cc + i * 8] = src[i];
    }
    __syncthreads();

    f32x4 acc[4][2];
    #pragma unroll
    for (int mi = 0; mi < 4; ++mi)
      #pragma unroll
      for (int ni = 0; ni < 2; ++ni)
        acc[mi][ni] = (f32x4){0.f, 0.f, 0.f, 0.f};

    #pragma unroll
    for (int ks = 0; ks < 4; ++ks) {
      int kk = ks * 32 + lhi * 8;
      h8 a[4], bfr[2];
      #pragma unroll
      for (int mi = 0; mi < 4; ++mi)
        a[mi] = *(const h8*)&As[wm + mi * 16 + l16][kk];
      #pragma unroll
      for (int ni = 0; ni < 2; ++ni)
        bfr[ni] = *(const h8*)&Ws[wn + ni * 16 + l16][kk];
      #pragma unroll
      for (int mi = 0; mi < 4; ++mi)
        #pragma unroll
        for (int ni = 0; ni < 2; ++ni)
          acc[mi][ni] = __builtin_amdgcn_mfma_f32_16x16x32_f16(a[mi], bfr[ni], acc[mi][ni], 0, 0, 0);
    }

    #pragma unroll
    for (int mi = 0; mi < 4; ++mi)
      #pragma unroll
      for (int ni = 0; ni < 2; ++ni) {
        int col = nb * 64 + wn + ni * 16 + l16;
        float bv = bias[col];
        #pragma unroll
        for (int r = 0; r < 4; ++r) {
          int row = m0 + wm + mi * 16 + lhi * 4 + r;
          gi16[(size_t)row * G3 + col] = (_Float16)(acc[mi][ni][r] + bv);
        }
      }
    __syncthreads();
  }
}

// ---------------- recurrent kernel over one chunk ----------------
// 512 threads: thread = (Q = dim-pair 0..127, c = K-chunk 0..3).
// Weights: 6 gate-rows x 64 fp16 = 192 dwords/thread pinned to v64..v255.
__global__ __launch_bounds__(512, 2) void k_rnn(const _Float16* __restrict__ whh16,
    const _Float16* __restrict__ gi16, const float* __restrict__ bhnf,
    _Float16* __restrict__ outs16, float* __restrict__ hstate, int s0, int CH) {
  // logical dword D (f16-pair index 0..127) at phys (D>>5)*36 + (D&31)
  __shared__ __align__(16) unsigned int hsh[2][144];
  int b = blockIdx.x;
  int tid = threadIdx.x;
  int lane = tid & 63;
  int c = lane & 3;
  int Q = (tid >> 6) * 16 + (lane >> 2);  // 0..127
  int j0 = 2 * Q;

  uint4 wv[6][8];
  #pragma unroll
  for (int d = 0; d < 2; ++d)
    #pragma unroll
    for (int g = 0; g < 3; ++g) {
      const uint4* src = (const uint4*)(whh16 + (size_t)(g * 256 + j0 + d) * DH + c * 64);
      #pragma unroll
      for (int i = 0; i < 8; ++i) wv[d * 3 + g][i] = src[i];
    }

  float bn0 = bhnf[j0], bn1 = bhnf[j0 + 1];
  float h0, h1;
  if (s0 == 0) { h0 = 0.f; h1 = 0.f; }
  else { h0 = hstate[b * 256 + j0]; h1 = hstate[b * 256 + j0 + 1]; }

  int wr = (Q >> 5) * 36 + (Q & 31);  // phys write slot for this thread's pair
  if (c == 0) {
    union { _Float16 h[2]; unsigned int u; } pk;
    pk.h[0] = (_Float16)h0; pk.h[1] = (_Float16)h1;
    hsh[0][wr] = pk.u;
  }
  __syncthreads();

  const unsigned int* gi32 = (const unsigned int*)gi16;
  unsigned int* outs32 = (unsigned int*)outs16;
  size_t gbase = (size_t)b * 384 + Q;                       // chunk-local
  size_t obase = ((size_t)s0 * 64 + b) * 128 + Q;           // global
  int p = 0;

  for (int s = 0; s < CH; ++s) {
    // gi loads first: independent, issue early, latency hides under dot phase
    unsigned int gr = gi32[gbase];
    unsigned int gz = gi32[gbase + 128];
    unsigned int gn = gi32[gbase + 256];

    // IN-LOOP EXPLICIT-REGISTER PIN: each weight dword must sit in its named
    // VGPR at this point, every iteration. Zero instructions emitted.
    PIN4(wv[0][0],  64,  65,  66,  67);  PIN4(wv[0][1],  68,  69,  70,  71);
    PIN4(wv[0][2],  72,  73,  74,  75);  PIN4(wv[0][3],  76,  77,  78,  79);
    PIN4(wv[0][4],  80,  81,  82,  83);  PIN4(wv[0][5],  84,  85,  86,  87);
    PIN4(wv[0][6],  88,  89,  90,  91);  PIN4(wv[0][7],  92,  93,  94,  95);
    PIN4(wv[1][0],  96,  97,  98,  99);  PIN4(wv[1][1], 100, 101, 102, 103);
    PIN4(wv[1][2], 104, 105, 106, 107);  PIN4(wv[1][3], 108, 109, 110, 111);
    PIN4(wv[1][4], 112, 113, 114, 115);  PIN4(wv[1][5], 116, 117, 118, 119);
    PIN4(wv[1][6], 120, 121, 122, 123);  PIN4(wv[1][7], 124, 125, 126, 127);
    PIN4(wv[2][0], 128, 129, 130, 131);  PIN4(wv[2][1], 132, 133, 134, 135);
    PIN4(wv[2][2], 136, 137, 138, 139);  PIN4(wv[2][3], 140, 141, 142, 143);
    PIN4(wv[2][4], 144, 145, 146, 147);  PIN4(wv[2][5], 148, 149, 150, 151);
    PIN4(wv[2][6], 152, 153, 154, 155);  PIN4(wv[2][7], 156, 157, 158, 159);
    PIN4(wv[3][0], 160, 161, 162, 163);  PIN4(wv[3][1], 164, 165, 166, 167);
    PIN4(wv[3][2], 168, 169, 170, 171);  PIN4(wv[3][3], 172, 173, 174, 175);
    PIN4(wv[3][4], 176, 177, 178, 179);  PIN4(wv[3][5], 180, 181, 182, 183);
    PIN4(wv[3][6], 184, 185, 186, 187);  PIN4(wv[3][7], 188, 189, 190, 191);
    PIN4(wv[4][0], 192, 193, 194, 195);  PIN4(wv[4][1], 196, 197, 198, 199);
    PIN4(wv[4][2], 200, 201, 202, 203);  PIN4(wv[4][3], 204, 205, 206, 207);
    PIN4(wv[4][4], 208, 209, 210, 211);  PIN4(wv[4][5], 212, 213, 214, 215);
    PIN4(wv[4][6], 216, 217, 218, 219);  PIN4(wv[4][7], 220, 221, 222, 223);
    PIN4(wv[5][0], 224, 225, 226, 227);  PIN4(wv[5][1], 228, 229, 230, 231);
    PIN4(wv[5][2], 232, 233, 234, 235);  PIN4(wv[5][3], 236, 237, 238, 239);
    PIN4(wv[5][4], 240, 241, 242, 243);  PIN4(wv[5][5], 244, 245, 246, 247);
    PIN4(wv[5][6], 248, 249, 250, 251);  PIN4(wv[5][7], 252, 253, 254, 255);

    const uint4* hp = (const uint4*)&hsh[p][c * 36];
    float a0 = 0.f, a1 = 0.f, a2 = 0.f, a3 = 0.f, a4 = 0.f, a5 = 0.f;
    #pragma unroll
    for (int u = 0; u < 8; ++u) {
      uint4 hv = hp[u];
      a0 = fd2(wv[0][u].x, hv.x, a0); a0 = fd2(wv[0][u].y, hv.y, a0);
      a0 = fd2(wv[0][u].z, hv.z, a0); a0 = fd2(wv[0][u].w, hv.w, a0);
      a1 = fd2(wv[1][u].x, hv.x, a1); a1 = fd2(wv[1][u].y, hv.y, a1);
      a1 = fd2(wv[1][u].z, hv.z, a1); a1 = fd2(wv[1][u].w, hv.w, a1);
      a2 = fd2(wv[2][u].x, hv.x, a2); a2 = fd2(wv[2][u].y, hv.y, a2);
      a2 = fd2(wv[2][u].z, hv.z, a2); a2 = fd2(wv[2][u].w, hv.w, a2);
      a3 = fd2(wv[3][u].x, hv.x, a3); a3 = fd2(wv[3][u].y, hv.y, a3);
      a3 = fd2(wv[3][u].z, hv.z, a3); a3 = fd2(wv[3][u].w, hv.w, a3);
      a4 = fd2(wv[4][u].x, hv.x, a4); a4 = fd2(wv[4][u].y, hv.y, a4);
      a4 = fd2(wv[4][u].z, hv.z, a4); a4 = fd2(wv[4][u].w, hv.w, a4);
      a5 = fd2(wv[5][u].x, hv.x, a5); a5 = fd2(wv[5][u].y, hv.y, a5);
      a5 = fd2(wv[5][u].z, hv.z, a5); a5 = fd2(wv[5][u].w, hv.w, a5);
    }
    // 4-lane butterfly via DPP quad_perm (pure VALU, sum lands in all 4 lanes)
    a0 = dppadd<0xB1>(a0); a0 = dppadd<0x4E>(a0);
    a1 = dppadd<0xB1>(a1); a1 = dppadd<0x4E>(a1);
    a2 = dppadd<0xB1>(a2); a2 = dppadd<0x4E>(a2);
    a3 = dppadd<0xB1>(a3); a3 = dppadd<0x4E>(a3);
    a4 = dppadd<0xB1>(a4); a4 = dppadd<0x4E>(a4);
    a5 = dppadd<0xB1>(a5); a5 = dppadd<0x4E>(a5);

    h2 grh = __builtin_bit_cast(h2, gr);
    h2 gzh = __builtin_bit_cast(h2, gz);
    h2 gnh = __builtin_bit_cast(h2, gn);
    {
      float r = 1.f / (1.f + __expf(-((float)grh[0] + a0)));
      float z = 1.f / (1.f + __expf(-((float)gzh[0] + a1)));
      float x = (float)gnh[0] + r * (a2 + bn0);
      float n = 1.f - 2.f / (__expf(2.f * x) + 1.f);
      h0 = n + z * (h0 - n);
    }
    {
      float r = 1.f / (1.f + __expf(-((float)grh[1] + a3)));
      float z = 1.f / (1.f + __expf(-((float)gzh[1] + a4)));
      float x = (float)gnh[1] + r * (a5 + bn1);
      float n = 1.f - 2.f / (__expf(2.f * x) + 1.f);
      h1 = n + z * (h1 - n);
    }
    union { _Float16 h[2]; unsigned int u; } pk;
    pk.h[0] = (_Float16)h0; pk.h[1] = (_Float16)h1;
    if (c == 0) {
      hsh[p ^ 1][wr] = pk.u;
      outs32[obase] = pk.u;
    }
    __syncthreads();
    p ^= 1;
    gbase += 64 * 384;
    obase += 64 * 128;
  }

  if (c == 0) {
    hstate[b * 256 + j0] = h0;
    hstate[b * 256 + j0 + 1] = h1;
  }
}

// ---------------- attention: scores ----------------
__global__ __launch_bounds__(256) void k_scores(const _Float16* __restrict__ outs16,
    const float* __restrict__ watt, float* __restrict__ scores) {
  int idx = blockIdx.x * 4 + (threadIdx.x >> 6);  // sb index
  int lane = threadIdx.x & 63;
  const uint2* row = (const uint2*)((const unsigned int*)outs16 + (size_t)idx * 128 + lane * 2);
  uint2 v = *row;
  float4 w = *(const float4*)(watt + lane * 4);
  h2 va = __builtin_bit_cast(h2, v.x);
  h2 vb = __builtin_bit_cast(h2, v.y);
  float sum = (float)va[0] * w.x + (float)va[1] * w.y + (float)vb[0] * w.z + (float)vb[1] * w.w;
  #pragma unroll
  for (int m = 1; m < 64; m <<= 1) sum += __shfl_xor(sum, m);
  if (lane == 0) scores[idx] = sum;
}

// ---------------- attention: softmax + weighted sum ----------------
__global__ __launch_bounds__(256) void k_att(const _Float16* __restrict__ outs16,
    const float* __restrict__ scores, float* __restrict__ out) {
  __shared__ float al[SEQ];
  __shared__ float red[12];
  int b = blockIdx.x, t = threadIdx.x;
  float v[8];
  float m = -1e30f;
  #pragma unroll
  for (int i = 0; i < 8; ++i) {
    v[i] = scores[(size_t)(t + i * 256) * 64 + b];
    m = fmaxf(m, v[i]);
  }
  #pragma unroll
  for (int k = 1; k < 64; k <<= 1) m = fmaxf(m, __shfl_xor(m, k));
  if ((t & 63) == 0) red[t >> 6] = m;
  __syncthreads();
  m = fmaxf(fmaxf(red[0], red[1]), fmaxf(red[2], red[3]));
  float l = 0.f;
  #pragma unroll
  for (int i = 0; i < 8; ++i) {
    float e = __expf(v[i] - m);
    al[t + i * 256] = e;
    l += e;
  }
  #pragma unroll
  for (int k = 1; k < 64; k <<= 1) l += __shfl_xor(l, k);
  if ((t & 63) == 0) red[8 + (t >> 6)] = l;
  __syncthreads();
  l = red[8] + red[9] + red[10] + red[11];
  float inv = 1.f / l;

  float acc = 0.f;
  const unsigned int* o32 = (const unsigned int*)outs16;
  size_t base = (size_t)b * 128 + (t >> 1);
  int hi = t & 1;
  for (int s = 0; s < SEQ; ++s) {
    unsigned int u = o32[base + (size_t)s * 8192];
    h2 hh = __builtin_bit_cast(h2, u);
    acc += al[s] * (float)hh[hi];
  }
  out[b * 256 + t] = acc * inv;
}

__global__ __launch_bounds__(256) void k_fill(float* out, float v, int n) {
  int i = blockIdx.x * 256 + threadIdx.x;
  if (i < n) out[i] = v;
}

// ---------------- launch ----------------
extern "C" void kernel_launch(void* const* d_in, const int* in_sizes, int n_in,
                              void* d_out, int out_size, void* d_ws, size_t ws_size,
                              hipStream_t stream) {
  const float* data = (const float*)d_in[0];
  const float* wih  = (const float*)d_in[1];
  const float* whh  = (const float*)d_in[2];
  const float* bih  = (const float*)d_in[3];
  const float* bhh  = (const float*)d_in[4];
  const float* watt = (const float*)d_in[5];
  float* out = (float*)d_out;

  const size_t OFF_WIH    = 0;           //    196,608
  const size_t OFF_WHH    = 196608;      //    393,216
  const size_t OFF_BIAS   = 589824;      //      3,072
  const size_t OFF_BHN    = 592896;      //      1,024
  const size_t OFF_H      = 593920;      //     65,536
  const size_t OFF_SCORES = 659456;      //    524,288
  const size_t OFF_OUTS   = 1183744;     // 67,108,864
  const size_t OFF_GI     = 68292608;

  int CH = 0;
  for (int ch = SEQ; ch >= 64; ch >>= 1) {
    if (OFF_GI + (size_t)ch * 64 * G3 * 2 <= ws_size) { CH = ch; break; }
  }
  if (CH == 0) {
    k_fill<<<(out_size + 255) / 256, 256, 0, stream>>>(out, 2.0e6f, out_size);
    return;
  }

  char* ws = (char*)d_ws;
  _Float16* wih16  = (_Float16*)(ws + OFF_WIH);
  _Float16* whh16  = (_Float16*)(ws + OFF_WHH);
  float*    biasf  = (float*)(ws + OFF_BIAS);
  float*    bhnf   = (float*)(ws + OFF_BHN);
  float*    hstate = (float*)(ws + OFF_H);
  float*    scores = (float*)(ws + OFF_SCORES);
  _Float16* outs16 = (_Float16*)(ws + OFF_OUTS);
  _Float16* gi16   = (_Float16*)(ws + OFF_GI);

  k_prep_w<<<(98304 + 196608 + 768 + 256 + 255) / 256, 256, 0, stream>>>(
      wih, whh, bih, bhh, wih16, whh16, biasf, bhnf);

  for (int s0 = 0; s0 < SEQ; s0 += CH) {
    k_gi<<<CH * 64 / 128, 256, 0, stream>>>(data, wih16, biasf, gi16, s0);
    k_rnn<<<BATCH, 512, 0, stream>>>(whh16, gi16, bhnf, outs16, hstate, s0, CH);
  }

  k_scores<<<SEQ * BATCH / 4, 256, 0, stream>>>(outs16, watt, scores);
  k_att<<<BATCH, 256, 0, stream>>>(outs16, scores, out);
}